// Round 1
// baseline (335.242 us; speedup 1.0000x reference)
//
#include <hip/hip_runtime.h>

// Problem constants (fixed by setup_inputs)
constexpr int B = 4;
constexpr int N = 768;
constexpr int D = 16;           // per-node embedding dim
constexpr int E = 12288;        // edges per batch
constexpr int NN = N * N;       // 589824 pairs per batch
constexpr int PAIRS = B * NN;   // 2,359,296
// d_out layout (fp32, concatenated in return order):
//   [0, B*NN*2D)                      edge_embeddings
//   [B*NN*2D, B*NN*2D + B*NN)         logits
//   [.. + B*NN, .. + 2*B*NN)          truth
constexpr long long EE_FLOATS = (long long)PAIRS * 2 * D;  // 75,497,472

__device__ __forceinline__ float dot4(float4 a, float4 b) {
    return a.x * b.x + a.y * b.y + a.z * b.z + a.w * b.w;
}
__device__ __forceinline__ float absdiff4(float4 a, float4 b) {
    return fabsf(a.x - b.x) + fabsf(a.y - b.y) + fabsf(a.z - b.z) + fabsf(a.w - b.w);
}

// Fused K1+K2: one block per (b,i) row of the N x N pair matrix.
//
// Main loop (EE fill, 24 iters): float4 index f = t + k*256 within the row's
// 6144 float4s; pair j = f>>3, quarter q = f&7. Since 256 ≡ 0 (mod 8), each
// lane's q is loop-invariant:
//   q<4  lanes: value = e_i quarter q  -> held in a register, pure stores
//   q>=4 lanes: value = e_j quarter q-4 -> coalesced L1/L2-hot load, 24-deep ILP
// Per-wave store = 64 x 16B = 1 KiB contiguous -> full write coalescing.
//
// Tail loop: logits + truth zeroing for the row. dot(e_i,W1)+bias is
// row-constant; each thread finishes 3 j's (dot(e_j,W2), |e_i-e_j| mask).
__global__ __launch_bounds__(256) void row_fused_kernel(
    const float4* __restrict__ emb4, const float* __restrict__ W,
    const float* __restrict__ bias, float4* __restrict__ ee4,
    float* __restrict__ logits, float* __restrict__ truth) {
    const int row = blockIdx.x;          // = b*N + i
    const int b = row / N;
    const int i = row - b * N;
    const float4* __restrict__ eb = emb4 + (size_t)b * N * 4;  // batch base (4 float4/node)
    const float4* __restrict__ ei = eb + i * 4;

    const int t = threadIdx.x;
    const int q = t & 7;
    const int qq = q & 3;
    const bool isI = (q < 4);
    const float4 eiq = ei[qq];           // broadcast; used by q<4 lanes

    float4* __restrict__ orow = ee4 + (size_t)row * (N * 8);
#pragma unroll
    for (int k = 0; k < (N * 8) / 256; ++k) {   // 24 iterations
        const int f = t + k * 256;
        float4 v = eiq;
        if (!isI) v = eb[(f >> 3) * 4 + qq];
        orow[f] = v;
    }

    // ---- logits + truth zeroing for this row ----
    const float4* __restrict__ W4 = (const float4*)W;  // 8 float4 = 32 weights
    const float4 wa0 = W4[0], wa1 = W4[1], wa2 = W4[2], wa3 = W4[3];
    const float4 wb0 = W4[4], wb1 = W4[5], wb2 = W4[6], wb3 = W4[7];
    const float4 e0 = ei[0], e1 = ei[1], e2 = ei[2], e3 = ei[3];
    const float base =
        dot4(e0, wa0) + dot4(e1, wa1) + dot4(e2, wa2) + dot4(e3, wa3) + bias[0];
    float* __restrict__ lrow = logits + (size_t)row * N;
    float* __restrict__ trow = truth + (size_t)row * N;
#pragma unroll
    for (int k = 0; k < N / 256; ++k) {          // 3 iterations
        const int j = t + k * 256;
        const float4* __restrict__ ej = eb + j * 4;
        const float4 c0 = ej[0], c1 = ej[1], c2 = ej[2], c3 = ej[3];
        const float acc = base + dot4(c0, wb0) + dot4(c1, wb1) +
                          dot4(c2, wb2) + dot4(c3, wb3);
        const float diff = absdiff4(e0, c0) + absdiff4(e1, c1) +
                           absdiff4(e2, c2) + absdiff4(e3, c3);
        lrow[j] = (diff != 0.f) ? acc : -10.0f;
        trow[j] = 0.0f;
    }
}

// K3: scatter ground-truth edges. edges layout [B, 2, E]; duplicates are
// idempotent (plain store of 1.0). Runs after row_fused_kernel's zeroing
// (same stream => ordered).
__global__ void truth_scatter_kernel(const int* __restrict__ edges,
                                     float* __restrict__ truth) {
    int tid = blockIdx.x * blockDim.x + threadIdx.x;
    if (tid >= B * E) return;
    int b = tid / E;
    int e = tid - b * E;
    int src = edges[b * 2 * E + e];
    int dst = edges[b * 2 * E + E + e];
    truth[(size_t)b * NN + src * N + dst] = 1.0f;
}

extern "C" void kernel_launch(void* const* d_in, const int* in_sizes, int n_in,
                              void* d_out, int out_size, void* d_ws, size_t ws_size,
                              hipStream_t stream) {
    const float4* emb4 = (const float4*)d_in[0];       // [B,N,D] fp32, D=16 -> 4 float4/node
    const int* edges = (const int*)d_in[1];            // [B,2,E]
    const float* W = (const float*)d_in[2];            // [2D]
    const float* bias = (const float*)d_in[3];         // [1]

    float* out = (float*)d_out;
    float* ee = out;
    float* logits = out + EE_FLOATS;
    float* truth = out + EE_FLOATS + (long long)PAIRS;

    // Fused EE fill + logits + truth zeroing: one block per (b,i) row.
    row_fused_kernel<<<B * N, 256, 0, stream>>>(emb4, W, bias, (float4*)ee,
                                                logits, truth);
    // Edge scatter into truth.
    truth_scatter_kernel<<<(B * E + 255) / 256, 256, 0, stream>>>(edges, truth);
}